// Round 1
// baseline (265.090 us; speedup 1.0000x reference)
//
#include <hip/hip_runtime.h>
#include <hip/hip_bf16.h>

#define TCH 512
#define MTOT 16384
#define SEQ 2048
#define LN_EPS 1e-5f

typedef __attribute__((ext_vector_type(8))) __bf16 bf16x8;
typedef __attribute__((ext_vector_type(4))) float f32x4;

__device__ __forceinline__ void st_ln(float* p, float v) { *p = v; }
__device__ __forceinline__ void st_ln(__hip_bfloat16* p, float v) { *p = __float2bfloat16(v); }

// ---------------- prep: w1,w2 -> bf16; wo -> wo_eff (fold HEADS copies) ----
__global__ __launch_bounds__(256) void prep_kernel(
    const float* __restrict__ w1, const float* __restrict__ w2,
    const float* __restrict__ wo,
    __hip_bfloat16* __restrict__ w1b, __hip_bfloat16* __restrict__ w2b,
    float4* __restrict__ wo_eff4)
{
  int i = blockIdx.x * 256 + threadIdx.x;   // grid covers 512*512 exactly
  w1b[i] = __float2bfloat16(w1[i]);
  w2b[i] = __float2bfloat16(w2[i]);
  if (i < TCH) {
    float s0 = 0.f, s1 = 0.f, s2 = 0.f;
    #pragma unroll
    for (int h = 0; h < 6; ++h) {
      s0 += wo[i*18 + h*3 + 0];
      s1 += wo[i*18 + h*3 + 1];
      s2 += wo[i*18 + h*3 + 2];
    }
    wo_eff4[i] = make_float4(s0, s1, s2, 0.f);
  }
}

// ---------------- qkv projection: one wave per (b,s) row --------------------
__global__ __launch_bounds__(256) void qkv_kernel(
    const float* __restrict__ x,
    const float* __restrict__ wq, const float* __restrict__ bq,
    const float* __restrict__ wk, const float* __restrict__ bk,
    const float* __restrict__ wv, const float* __restrict__ bv,
    float4* __restrict__ q4, float4* __restrict__ k4, float4* __restrict__ v4)
{
  __shared__ float wsh[9 * TCH];
  for (int i = threadIdx.x; i < 9 * TCH; i += 256) {
    float w;
    if (i < 1536)      w = wq[i];
    else if (i < 3072) w = wk[i - 1536];
    else               w = wv[i - 3072];
    wsh[i] = w;
  }
  __syncthreads();

  const int lane = threadIdx.x & 63;
  const int wid  = blockIdx.x * 4 + (threadIdx.x >> 6);   // 0..16383
  const float4* xr = reinterpret_cast<const float4*>(x + (size_t)wid * TCH);
  const float4 xa = xr[lane * 2], xb = xr[lane * 2 + 1];

  float d[9];
  #pragma unroll
  for (int m = 0; m < 9; ++m) {
    const float4* wr = reinterpret_cast<const float4*>(wsh + m * TCH);
    float4 wa = wr[lane * 2], wb = wr[lane * 2 + 1];
    d[m] = xa.x*wa.x + xa.y*wa.y + xa.z*wa.z + xa.w*wa.w
         + xb.x*wb.x + xb.y*wb.y + xb.z*wb.z + xb.w*wb.w;
  }
  #pragma unroll
  for (int off = 1; off < 64; off <<= 1) {
    #pragma unroll
    for (int m = 0; m < 9; ++m) d[m] += __shfl_xor(d[m], off, 64);
  }
  if (lane == 0) {
    q4[wid] = make_float4(d[0] + bq[0], d[1] + bq[1], d[2] + bq[2], 0.f);
    k4[wid] = make_float4(d[3] + bk[0], d[4] + bk[1], d[5] + bk[2], 0.f);
    v4[wid] = make_float4(d[6] + bv[0], d[7] + bv[1], d[8] + bv[2], 0.f);
  }
}

// ---------------- attention + z@wo_eff epilogue -----------------------------
// grid = 512 blocks: blockIdx>>6 = batch, blockIdx&63 = 32-query chunk.
// Stage K,V of the batch in LDS (64 KB); each wave handles 8 queries.
__global__ __launch_bounds__(256) void attn_kernel(
    const float4* __restrict__ q4, const float4* __restrict__ k4,
    const float4* __restrict__ v4,
    const float4* __restrict__ wo_eff4, const float* __restrict__ bo,
    __hip_bfloat16* __restrict__ z2b)
{
  __shared__ float4 kk[SEQ];
  __shared__ float4 vv[SEQ];
  const int b    = blockIdx.x >> 6;
  const int qc   = blockIdx.x & 63;
  const int base = b * SEQ;
  for (int i = threadIdx.x; i < SEQ; i += 256) {
    kk[i] = k4[base + i];
    vv[i] = v4[base + i];
  }
  __syncthreads();

  const int wave = threadIdx.x >> 6;
  const int lane = threadIdx.x & 63;

  for (int qi = 0; qi < 8; ++qi) {
    const int row = base + qc * 32 + wave * 8 + qi;
    const float4 q = q4[row];
    float sc[32];
    float mx = -1e30f;
    #pragma unroll
    for (int i = 0; i < 32; ++i) {
      float4 k = kk[i * 64 + lane];
      float s = (q.x*k.x + q.y*k.y + q.z*k.z) * 0.57735026919f; // 1/sqrt(3)
      sc[i] = s;
      mx = fmaxf(mx, s);
    }
    #pragma unroll
    for (int off = 1; off < 64; off <<= 1) mx = fmaxf(mx, __shfl_xor(mx, off, 64));

    float sum = 0.f, a0 = 0.f, a1 = 0.f, a2 = 0.f;
    #pragma unroll
    for (int i = 0; i < 32; ++i) {
      float p = __expf(sc[i] - mx);
      float4 v = vv[i * 64 + lane];
      sum += p; a0 += p * v.x; a1 += p * v.y; a2 += p * v.z;
    }
    #pragma unroll
    for (int off = 1; off < 64; off <<= 1) {
      sum += __shfl_xor(sum, off, 64);
      a0  += __shfl_xor(a0,  off, 64);
      a1  += __shfl_xor(a1,  off, 64);
      a2  += __shfl_xor(a2,  off, 64);
    }
    const float inv = 1.f / sum;
    const float z0 = a0 * inv, z1 = a1 * inv, z2 = a2 * inv;

    __hip_bfloat16* outr = z2b + (size_t)row * TCH;
    for (int c = lane; c < TCH; c += 64) {
      float4 we = wo_eff4[c];
      outr[c] = __float2bfloat16(z0*we.x + z1*we.y + z2*we.z + bo[c]);
    }
  }
}

// ---------------- fused GEMM (C = A @ W^T + bias) + residual + LayerNorm ----
// Block: 512 threads (8 waves), 64 rows x full 512 cols. Wave w owns cols
// [w*64, w*64+64). mfma_f32_16x16x32_bf16: A-frag A[m=lane&15][k=quad*8+j],
// B-frag W[n=lane&15][k=quad*8+j], D[row=quad*4+reg][col=lane&15].
template<typename LN_T, bool WRITE_R>
__global__ __launch_bounds__(512) void gemm_ln_kernel(
    const __hip_bfloat16* __restrict__ A,   // [16384, 512] bf16
    const __hip_bfloat16* __restrict__ W,   // [512, 512]   bf16, row = out dim
    const float* __restrict__ bias,         // [512]
    const float* __restrict__ res,          // [16384, 512] fp32 residual
    float* __restrict__ Rout,               // r = res + C (if WRITE_R)
    LN_T* __restrict__ LNout,               // LayerNorm(r)
    const float* __restrict__ gamma, const float* __restrict__ beta)
{
  const int row0 = blockIdx.x * 64;
  const int wave = threadIdx.x >> 6;
  const int lane = threadIdx.x & 63;
  const int l16  = lane & 15;
  const int quad = lane >> 4;
  const int n0   = wave * 64;

  f32x4 acc[4][4] = {};

  for (int k0 = 0; k0 < TCH; k0 += 32) {
    const int ka = k0 + quad * 8;
    bf16x8 af[4], bf[4];
    #pragma unroll
    for (int mt = 0; mt < 4; ++mt)
      af[mt] = *reinterpret_cast<const bf16x8*>(A + (size_t)(row0 + mt*16 + l16) * TCH + ka);
    #pragma unroll
    for (int nt = 0; nt < 4; ++nt)
      bf[nt] = *reinterpret_cast<const bf16x8*>(W + (size_t)(n0 + nt*16 + l16) * TCH + ka);
    #pragma unroll
    for (int mt = 0; mt < 4; ++mt)
      #pragma unroll
      for (int nt = 0; nt < 4; ++nt)
        acc[mt][nt] = __builtin_amdgcn_mfma_f32_16x16x32_bf16(af[mt], bf[nt], acc[mt][nt], 0, 0, 0);
  }

  __shared__ float redS[8][64];
  __shared__ float redQ[8][64];

  #pragma unroll
  for (int mt = 0; mt < 4; ++mt) {
    #pragma unroll
    for (int r = 0; r < 4; ++r) {
      const int lrow = mt*16 + quad*4 + r;
      const int grow = row0 + lrow;
      float s = 0.f, sq = 0.f;
      #pragma unroll
      for (int nt = 0; nt < 4; ++nt) {
        const int col = n0 + nt*16 + l16;
        float v = acc[mt][nt][r] + bias[col] + res[(size_t)grow * TCH + col];
        acc[mt][nt][r] = v;
        if constexpr (WRITE_R) Rout[(size_t)grow * TCH + col] = v;
        s += v; sq += v * v;
      }
      #pragma unroll
      for (int off = 1; off < 16; off <<= 1) {
        s  += __shfl_xor(s,  off, 64);
        sq += __shfl_xor(sq, off, 64);
      }
      if (l16 == 0) { redS[wave][lrow] = s; redQ[wave][lrow] = sq; }
    }
  }
  __syncthreads();

  #pragma unroll
  for (int mt = 0; mt < 4; ++mt) {
    #pragma unroll
    for (int r = 0; r < 4; ++r) {
      const int lrow = mt*16 + quad*4 + r;
      const int grow = row0 + lrow;
      float S = 0.f, Q = 0.f;
      #pragma unroll
      for (int w = 0; w < 8; ++w) { S += redS[w][lrow]; Q += redQ[w][lrow]; }
      const float mu  = S * (1.f / TCH);
      const float var = Q * (1.f / TCH) - mu * mu;
      const float rs  = rsqrtf(var + LN_EPS);
      #pragma unroll
      for (int nt = 0; nt < 4; ++nt) {
        const int col = n0 + nt*16 + l16;
        float v = (acc[mt][nt][r] - mu) * rs * gamma[col] + beta[col];
        st_ln(&LNout[(size_t)grow * TCH + col], v);
      }
    }
  }
}

// ---------------- host ------------------------------------------------------
extern "C" void kernel_launch(void* const* d_in, const int* in_sizes, int n_in,
                              void* d_out, int out_size, void* d_ws, size_t ws_size,
                              hipStream_t stream) {
  (void)in_sizes; (void)n_in; (void)out_size; (void)ws_size;
  const float* x     = (const float*)d_in[0];
  const float* wq    = (const float*)d_in[1];
  const float* bq    = (const float*)d_in[2];
  const float* wk    = (const float*)d_in[3];
  const float* bk    = (const float*)d_in[4];
  const float* wv    = (const float*)d_in[5];
  const float* bv    = (const float*)d_in[6];
  const float* wo    = (const float*)d_in[7];
  const float* bo    = (const float*)d_in[8];
  const float* w1    = (const float*)d_in[9];
  const float* b1    = (const float*)d_in[10];
  const float* w2    = (const float*)d_in[11];
  const float* b2    = (const float*)d_in[12];
  const float* gamma = (const float*)d_in[13];
  const float* beta  = (const float*)d_in[14];
  float* out = (float*)d_out;

  char* ws = (char*)d_ws;
  size_t off = 0;
  float4* q4      = (float4*)(ws + off); off += (size_t)MTOT * 16;        // 256 KB
  float4* k4      = (float4*)(ws + off); off += (size_t)MTOT * 16;        // 256 KB
  float4* v4      = (float4*)(ws + off); off += (size_t)MTOT * 16;        // 256 KB
  float4* wo_eff4 = (float4*)(ws + off); off += (size_t)TCH * 16;         // 8 KB
  __hip_bfloat16* w1b = (__hip_bfloat16*)(ws + off); off += (size_t)TCH * TCH * 2;   // 512 KB
  __hip_bfloat16* w2b = (__hip_bfloat16*)(ws + off); off += (size_t)TCH * TCH * 2;   // 512 KB
  __hip_bfloat16* z2b = (__hip_bfloat16*)(ws + off); off += (size_t)MTOT * TCH * 2;  // 16 MB
  __hip_bfloat16* r1b = (__hip_bfloat16*)(ws + off); off += (size_t)MTOT * TCH * 2;  // 16 MB
  float*          r0  = (float*)(ws + off);          off += (size_t)MTOT * TCH * 4;  // 32 MB

  prep_kernel<<<(TCH*TCH)/256, 256, 0, stream>>>(w1, w2, wo, w1b, w2b, wo_eff4);
  qkv_kernel<<<MTOT/4, 256, 0, stream>>>(x, wq, bq, wk, bk, wv, bv, q4, k4, v4);
  attn_kernel<<<512, 256, 0, stream>>>(q4, k4, v4, wo_eff4, bo, z2b);
  gemm_ln_kernel<__hip_bfloat16, true><<<MTOT/64, 512, 0, stream>>>(
      z2b, w1b, b1, x, r0, r1b, gamma, beta);
  gemm_ln_kernel<float, false><<<MTOT/64, 512, 0, stream>>>(
      r1b, w2b, b2, r0, nullptr, out, gamma, beta);
}

// Round 2
// 252.148 us; speedup vs baseline: 1.0513x; 1.0513x over previous
//
#include <hip/hip_runtime.h>
#include <hip/hip_bf16.h>

#define TCH 512
#define MTOT 16384
#define SEQ 2048
#define LN_EPS 1e-5f

typedef __attribute__((ext_vector_type(8))) __bf16 bf16x8;
typedef __attribute__((ext_vector_type(4))) float f32x4;

__device__ __forceinline__ void st_ln(float* p, float v) { *p = v; }
__device__ __forceinline__ void st_ln(__hip_bfloat16* p, float v) { *p = __float2bfloat16(v); }

// ---------------- prep: w1,w2 -> bf16; wo -> wo_eff (fold HEADS copies) ----
__global__ __launch_bounds__(256) void prep_kernel(
    const float* __restrict__ w1, const float* __restrict__ w2,
    const float* __restrict__ wo,
    __hip_bfloat16* __restrict__ w1b, __hip_bfloat16* __restrict__ w2b,
    float4* __restrict__ wo_eff4)
{
  int i = blockIdx.x * 256 + threadIdx.x;   // grid covers 512*512 exactly
  w1b[i] = __float2bfloat16(w1[i]);
  w2b[i] = __float2bfloat16(w2[i]);
  if (i < TCH) {
    float s0 = 0.f, s1 = 0.f, s2 = 0.f;
    #pragma unroll
    for (int h = 0; h < 6; ++h) {
      s0 += wo[i*18 + h*3 + 0];
      s1 += wo[i*18 + h*3 + 1];
      s2 += wo[i*18 + h*3 + 2];
    }
    wo_eff4[i] = make_float4(s0, s1, s2, 0.f);
  }
}

// ---------------- qkv projection: one wave per (b,s) row --------------------
__global__ __launch_bounds__(256) void qkv_kernel(
    const float* __restrict__ x,
    const float* __restrict__ wq, const float* __restrict__ bq,
    const float* __restrict__ wk, const float* __restrict__ bk,
    const float* __restrict__ wv, const float* __restrict__ bv,
    float4* __restrict__ q4, float4* __restrict__ k4, float4* __restrict__ v4)
{
  __shared__ float wsh[9 * TCH];
  for (int i = threadIdx.x; i < 9 * TCH; i += 256) {
    float w;
    if (i < 1536)      w = wq[i];
    else if (i < 3072) w = wk[i - 1536];
    else               w = wv[i - 3072];
    wsh[i] = w;
  }
  __syncthreads();

  const int lane = threadIdx.x & 63;
  const int wid  = blockIdx.x * 4 + (threadIdx.x >> 6);   // 0..16383
  const float4* xr = reinterpret_cast<const float4*>(x + (size_t)wid * TCH);
  const float4 xa = xr[lane * 2], xb = xr[lane * 2 + 1];

  float d[9];
  #pragma unroll
  for (int m = 0; m < 9; ++m) {
    const float4* wr = reinterpret_cast<const float4*>(wsh + m * TCH);
    float4 wa = wr[lane * 2], wb = wr[lane * 2 + 1];
    d[m] = xa.x*wa.x + xa.y*wa.y + xa.z*wa.z + xa.w*wa.w
         + xb.x*wb.x + xb.y*wb.y + xb.z*wb.z + xb.w*wb.w;
  }
  #pragma unroll
  for (int off = 1; off < 64; off <<= 1) {
    #pragma unroll
    for (int m = 0; m < 9; ++m) d[m] += __shfl_xor(d[m], off, 64);
  }
  if (lane == 0) {
    q4[wid] = make_float4(d[0] + bq[0], d[1] + bq[1], d[2] + bq[2], 0.f);
    k4[wid] = make_float4(d[3] + bk[0], d[4] + bk[1], d[5] + bk[2], 0.f);
    v4[wid] = make_float4(d[6] + bv[0], d[7] + bv[1], d[8] + bv[2], 0.f);
  }
}

// ---------------- attention + z@wo_eff epilogue (v2) ------------------------
// One query per lane; 64 queries per block; keys split across 8 waves
// (256 keys each) with K/V broadcast-read from LDS. No max-subtraction
// (scores are O(1), exp cannot overflow), so cross-wave combine is pure sum.
__global__ __launch_bounds__(512) void attn_kernel(
    const float4* __restrict__ q4, const float4* __restrict__ k4,
    const float4* __restrict__ v4,
    const float4* __restrict__ wo_eff4, const float* __restrict__ bo,
    __hip_bfloat16* __restrict__ z2b)
{
  __shared__ float4 kk[SEQ];   // 32 KB
  __shared__ float4 vv[SEQ];   // 32 KB
  const int b    = blockIdx.x >> 5;        // 32 blocks per batch
  const int qc   = blockIdx.x & 31;        // which 64-query chunk
  const int base = b * SEQ;
  const int tid  = threadIdx.x;
  for (int i = tid; i < SEQ; i += 512) {
    kk[i] = k4[base + i];
    vv[i] = v4[base + i];
  }
  __syncthreads();

  const int wave = tid >> 6;
  const int lane = tid & 63;
  const float4 q = q4[base + qc * 64 + lane];
  const float qx = q.x * 0.57735026919f;
  const float qy = q.y * 0.57735026919f;
  const float qz = q.z * 0.57735026919f;

  float l = 0.f, a0 = 0.f, a1 = 0.f, a2 = 0.f;
  const int i0 = wave * 256;
  #pragma unroll 4
  for (int i = i0; i < i0 + 256; ++i) {
    float4 K = kk[i];           // broadcast — conflict-free
    float4 V = vv[i];
    float p = __expf(qx*K.x + qy*K.y + qz*K.z);
    l += p; a0 += p*V.x; a1 += p*V.y; a2 += p*V.z;
  }
  __syncthreads();              // all waves done reading kk/vv

  float4* part = kk;            // alias: part[w*64 + q]
  part[wave * 64 + lane] = make_float4(l, a0, a1, a2);
  __syncthreads();

  float4* zb = vv;              // alias: z per local query
  if (tid < 64) {
    float L = 0.f, A0 = 0.f, A1 = 0.f, A2 = 0.f;
    #pragma unroll
    for (int w = 0; w < 8; ++w) {
      float4 p = part[w * 64 + tid];
      L += p.x; A0 += p.y; A1 += p.z; A2 += p.w;
    }
    const float inv = 1.f / L;
    zb[tid] = make_float4(A0 * inv, A1 * inv, A2 * inv, 0.f);
  }
  __syncthreads();

  // epilogue: wave w writes rows [w*8, w*8+8) of this 64-query chunk
  for (int qi = 0; qi < 8; ++qi) {
    const int qloc = wave * 8 + qi;
    const float4 z = zb[qloc];
    __hip_bfloat16* outr = z2b + (size_t)(base + qc * 64 + qloc) * TCH;
    #pragma unroll
    for (int it = 0; it < 8; ++it) {
      const int c = it * 64 + lane;
      const float4 we = wo_eff4[c];
      outr[c] = __float2bfloat16(z.x*we.x + z.y*we.y + z.z*we.z + bo[c]);
    }
  }
}

// ---------------- fused GEMM (C = A @ W^T + bias) + residual + LayerNorm ----
// Block: 512 threads (8 waves), 64 rows x full 512 cols. Wave w owns cols
// [w*64, w*64+64). Register double-buffer prefetch across k-steps.
template<typename LN_T, bool WRITE_R>
__global__ __launch_bounds__(512) void gemm_ln_kernel(
    const __hip_bfloat16* __restrict__ A,   // [16384, 512] bf16
    const __hip_bfloat16* __restrict__ W,   // [512, 512]   bf16, row = out dim
    const float* __restrict__ bias,         // [512]
    const float* __restrict__ res,          // [16384, 512] fp32 residual
    float* __restrict__ Rout,               // r = res + C (if WRITE_R)
    LN_T* __restrict__ LNout,               // LayerNorm(r)
    const float* __restrict__ gamma, const float* __restrict__ beta)
{
  const int row0 = blockIdx.x * 64;
  const int wave = threadIdx.x >> 6;
  const int lane = threadIdx.x & 63;
  const int l16  = lane & 15;
  const int quad = lane >> 4;
  const int n0   = wave * 64;

  f32x4 acc[4][4] = {};

  const __hip_bfloat16* Abase = A + (size_t)(row0 + l16) * TCH + quad * 8;
  const __hip_bfloat16* Wbase = W + (size_t)(n0   + l16) * TCH + quad * 8;

  bf16x8 afc[4], bfc[4], afn[4], bfn[4];
  #pragma unroll
  for (int t = 0; t < 4; ++t) {
    afc[t] = *reinterpret_cast<const bf16x8*>(Abase + (size_t)t * 16 * TCH);
    bfc[t] = *reinterpret_cast<const bf16x8*>(Wbase + (size_t)t * 16 * TCH);
  }

  for (int k0 = 0; k0 < TCH; k0 += 32) {
    if (k0 + 32 < TCH) {
      #pragma unroll
      for (int t = 0; t < 4; ++t) {
        afn[t] = *reinterpret_cast<const bf16x8*>(Abase + (size_t)t * 16 * TCH + k0 + 32);
        bfn[t] = *reinterpret_cast<const bf16x8*>(Wbase + (size_t)t * 16 * TCH + k0 + 32);
      }
    }
    #pragma unroll
    for (int mt = 0; mt < 4; ++mt)
      #pragma unroll
      for (int nt = 0; nt < 4; ++nt)
        acc[mt][nt] = __builtin_amdgcn_mfma_f32_16x16x32_bf16(afc[mt], bfc[nt], acc[mt][nt], 0, 0, 0);
    #pragma unroll
    for (int t = 0; t < 4; ++t) { afc[t] = afn[t]; bfc[t] = bfn[t]; }
  }

  __shared__ float redS[8][64];
  __shared__ float redQ[8][64];

  #pragma unroll
  for (int mt = 0; mt < 4; ++mt) {
    #pragma unroll
    for (int r = 0; r < 4; ++r) {
      const int lrow = mt*16 + quad*4 + r;
      const int grow = row0 + lrow;
      float s = 0.f, sq = 0.f;
      #pragma unroll
      for (int nt = 0; nt < 4; ++nt) {
        const int col = n0 + nt*16 + l16;
        float v = acc[mt][nt][r] + bias[col] + res[(size_t)grow * TCH + col];
        acc[mt][nt][r] = v;
        if constexpr (WRITE_R) Rout[(size_t)grow * TCH + col] = v;
        s += v; sq += v * v;
      }
      #pragma unroll
      for (int off = 1; off < 16; off <<= 1) {
        s  += __shfl_xor(s,  off, 64);
        sq += __shfl_xor(sq, off, 64);
      }
      if (l16 == 0) { redS[wave][lrow] = s; redQ[wave][lrow] = sq; }
    }
  }
  __syncthreads();

  #pragma unroll
  for (int mt = 0; mt < 4; ++mt) {
    #pragma unroll
    for (int r = 0; r < 4; ++r) {
      const int lrow = mt*16 + quad*4 + r;
      const int grow = row0 + lrow;
      float S = 0.f, Q = 0.f;
      #pragma unroll
      for (int w = 0; w < 8; ++w) { S += redS[w][lrow]; Q += redQ[w][lrow]; }
      const float mu  = S * (1.f / TCH);
      const float var = Q * (1.f / TCH) - mu * mu;
      const float rs  = rsqrtf(var + LN_EPS);
      #pragma unroll
      for (int nt = 0; nt < 4; ++nt) {
        const int col = n0 + nt*16 + l16;
        float v = (acc[mt][nt][r] - mu) * rs * gamma[col] + beta[col];
        st_ln(&LNout[(size_t)grow * TCH + col], v);
      }
    }
  }
}

// ---------------- host ------------------------------------------------------
extern "C" void kernel_launch(void* const* d_in, const int* in_sizes, int n_in,
                              void* d_out, int out_size, void* d_ws, size_t ws_size,
                              hipStream_t stream) {
  (void)in_sizes; (void)n_in; (void)out_size; (void)ws_size;
  const float* x     = (const float*)d_in[0];
  const float* wq    = (const float*)d_in[1];
  const float* bq    = (const float*)d_in[2];
  const float* wk    = (const float*)d_in[3];
  const float* bk    = (const float*)d_in[4];
  const float* wv    = (const float*)d_in[5];
  const float* bv    = (const float*)d_in[6];
  const float* wo    = (const float*)d_in[7];
  const float* bo    = (const float*)d_in[8];
  const float* w1    = (const float*)d_in[9];
  const float* b1    = (const float*)d_in[10];
  const float* w2    = (const float*)d_in[11];
  const float* b2    = (const float*)d_in[12];
  const float* gamma = (const float*)d_in[13];
  const float* beta  = (const float*)d_in[14];
  float* out = (float*)d_out;

  char* ws = (char*)d_ws;
  size_t off = 0;
  float4* q4      = (float4*)(ws + off); off += (size_t)MTOT * 16;        // 256 KB
  float4* k4      = (float4*)(ws + off); off += (size_t)MTOT * 16;        // 256 KB
  float4* v4      = (float4*)(ws + off); off += (size_t)MTOT * 16;        // 256 KB
  float4* wo_eff4 = (float4*)(ws + off); off += (size_t)TCH * 16;         // 8 KB
  __hip_bfloat16* w1b = (__hip_bfloat16*)(ws + off); off += (size_t)TCH * TCH * 2;   // 512 KB
  __hip_bfloat16* w2b = (__hip_bfloat16*)(ws + off); off += (size_t)TCH * TCH * 2;   // 512 KB
  __hip_bfloat16* z2b = (__hip_bfloat16*)(ws + off); off += (size_t)MTOT * TCH * 2;  // 16 MB
  __hip_bfloat16* r1b = (__hip_bfloat16*)(ws + off); off += (size_t)MTOT * TCH * 2;  // 16 MB
  float*          r0  = (float*)(ws + off);          off += (size_t)MTOT * TCH * 4;  // 32 MB

  prep_kernel<<<(TCH*TCH)/256, 256, 0, stream>>>(w1, w2, wo, w1b, w2b, wo_eff4);
  qkv_kernel<<<MTOT/4, 256, 0, stream>>>(x, wq, bq, wk, bk, wv, bv, q4, k4, v4);
  attn_kernel<<<MTOT/64, 512, 0, stream>>>(q4, k4, v4, wo_eff4, bo, z2b);
  gemm_ln_kernel<__hip_bfloat16, true><<<MTOT/64, 512, 0, stream>>>(
      z2b, w1b, b1, x, r0, r1b, gamma, beta);
  gemm_ln_kernel<float, false><<<MTOT/64, 512, 0, stream>>>(
      r1b, w2b, b2, r0, nullptr, out, gamma, beta);
}

// Round 3
// 248.201 us; speedup vs baseline: 1.0680x; 1.0159x over previous
//
#include <hip/hip_runtime.h>
#include <hip/hip_bf16.h>

#define TCH 512
#define MTOT 16384
#define SEQ 2048
#define LN_EPS 1e-5f

typedef __attribute__((ext_vector_type(8))) __bf16 bf16x8;
typedef __attribute__((ext_vector_type(4))) float f32x4;

__device__ __forceinline__ void st_ln(float* p, float v) { *p = v; }
__device__ __forceinline__ void st_ln(__hip_bfloat16* p, float v) { *p = __float2bfloat16(v); }
__device__ __forceinline__ float ld_res(const float* p) { return *p; }
__device__ __forceinline__ float ld_res(const __hip_bfloat16* p) { return __bfloat162float(*p); }

__device__ __forceinline__ unsigned pkbf(float a, float b) {
  union { __hip_bfloat16 h; unsigned short u; } ca, cb;
  ca.h = __float2bfloat16(a); cb.h = __float2bfloat16(b);
  return (unsigned)ca.u | ((unsigned)cb.u << 16);
}
__device__ __forceinline__ float bf_lo(unsigned u) { return __uint_as_float(u << 16); }
__device__ __forceinline__ float bf_hi(unsigned u) { return __uint_as_float(u & 0xffff0000u); }

// log2(e)/sqrt(3): folded into q so attention uses exp2 directly
#define QSCALE 0.8329517853860118f

// ---------------- prep: w1,w2 -> bf16; wo -> wo_eff (+bo in .w) -------------
__global__ __launch_bounds__(256) void prep_kernel(
    const float* __restrict__ w1, const float* __restrict__ w2,
    const float* __restrict__ wo, const float* __restrict__ bo,
    __hip_bfloat16* __restrict__ w1b, __hip_bfloat16* __restrict__ w2b,
    float4* __restrict__ wo_eff4)
{
  int i = blockIdx.x * 256 + threadIdx.x;   // grid covers 512*512 exactly
  w1b[i] = __float2bfloat16(w1[i]);
  w2b[i] = __float2bfloat16(w2[i]);
  if (i < TCH) {
    float s0 = 0.f, s1 = 0.f, s2 = 0.f;
    #pragma unroll
    for (int h = 0; h < 6; ++h) {
      s0 += wo[i*18 + h*3 + 0];
      s1 += wo[i*18 + h*3 + 1];
      s2 += wo[i*18 + h*3 + 2];
    }
    wo_eff4[i] = make_float4(s0, s1, s2, bo[i]);
  }
}

// ---------------- qkv projection: one wave per (b,s) row --------------------
// Emits q (fp32, pre-scaled by log2e/sqrt(3)) and packed bf16 {k0,k1,k2,v0,v1,v2}.
__global__ __launch_bounds__(256) void qkv_kernel(
    const float* __restrict__ x,
    const float* __restrict__ wq, const float* __restrict__ bq,
    const float* __restrict__ wk, const float* __restrict__ bk,
    const float* __restrict__ wv, const float* __restrict__ bv,
    float4* __restrict__ q4, uint4* __restrict__ kvp)
{
  __shared__ float wsh[9 * TCH];
  for (int i = threadIdx.x; i < 9 * TCH; i += 256) {
    float w;
    if (i < 1536)      w = wq[i];
    else if (i < 3072) w = wk[i - 1536];
    else               w = wv[i - 3072];
    wsh[i] = w;
  }
  __syncthreads();

  const int lane = threadIdx.x & 63;
  const int wid  = blockIdx.x * 4 + (threadIdx.x >> 6);   // 0..16383
  const float4* xr = reinterpret_cast<const float4*>(x + (size_t)wid * TCH);
  const float4 xa = xr[lane], xb = xr[64 + lane];   // 16B/lane contiguous

  float d[9];
  #pragma unroll
  for (int m = 0; m < 9; ++m) {
    const float4* wr = reinterpret_cast<const float4*>(wsh + m * TCH);
    float4 wa = wr[lane], wb = wr[64 + lane];       // conflict-free b128 pattern
    d[m] = xa.x*wa.x + xa.y*wa.y + xa.z*wa.z + xa.w*wa.w
         + xb.x*wb.x + xb.y*wb.y + xb.z*wb.z + xb.w*wb.w;
  }
  #pragma unroll
  for (int off = 1; off < 64; off <<= 1) {
    #pragma unroll
    for (int m = 0; m < 9; ++m) d[m] += __shfl_xor(d[m], off, 64);
  }
  if (lane == 0) {
    q4[wid] = make_float4((d[0] + bq[0]) * QSCALE,
                          (d[1] + bq[1]) * QSCALE,
                          (d[2] + bq[2]) * QSCALE, 0.f);
    float k0 = d[3] + bk[0], k1 = d[4] + bk[1], k2 = d[5] + bk[2];
    float v0 = d[6] + bv[0], v1 = d[7] + bv[1], v2 = d[8] + bv[2];
    kvp[wid] = make_uint4(pkbf(k0, k1), pkbf(k2, v0), pkbf(v1, v2), 0u);
  }
}

// ---------------- attention + z@wo_eff epilogue (v3) ------------------------
// 256 blocks x 1024 threads. One query per lane (64 queries/block); 16 waves
// split the 2048 keys (128 each). KV packed bf16 -> one broadcast
// ds_read_b128 per (wave,key). No max-subtraction (scores O(1)).
__global__ __launch_bounds__(1024) void attn_kernel(
    const float4* __restrict__ q4, const uint4* __restrict__ kvp,
    const float4* __restrict__ wo_eff4,
    __hip_bfloat16* __restrict__ z2b)
{
  __shared__ uint4  kv[SEQ];        // 32 KB
  __shared__ float4 part[16 * 64];  // 16 KB
  __shared__ float4 zbuf[64];       // 1 KB
  __shared__ float4 woL[TCH];       // 8 KB  (wo_eff + bo in .w)

  const int b    = blockIdx.x >> 5;        // 32 blocks per batch
  const int qc   = blockIdx.x & 31;        // which 64-query chunk
  const int base = b * SEQ;
  const int tid  = threadIdx.x;

  for (int i = tid; i < SEQ; i += 1024) kv[i] = kvp[base + i];
  for (int i = tid; i < TCH; i += 1024) woL[i] = wo_eff4[i];
  __syncthreads();

  const int wave = tid >> 6;
  const int lane = tid & 63;
  const float4 q = q4[base + qc * 64 + lane];  // pre-scaled

  float l = 0.f, a0 = 0.f, a1 = 0.f, a2 = 0.f;
  const int i0 = wave * 128;
  #pragma unroll 4
  for (int i = i0; i < i0 + 128; ++i) {
    uint4 w = kv[i];                         // broadcast — conflict-free
    float s = bf_lo(w.x) * q.x + bf_hi(w.x) * q.y + bf_lo(w.y) * q.z;
    float p = __builtin_amdgcn_exp2f(s);
    l  += p;
    a0 += p * bf_hi(w.y);
    a1 += p * bf_lo(w.z);
    a2 += p * bf_hi(w.z);
  }
  part[wave * 64 + lane] = make_float4(l, a0, a1, a2);
  __syncthreads();

  if (tid < 64) {
    float L = 0.f, A0 = 0.f, A1 = 0.f, A2 = 0.f;
    #pragma unroll
    for (int w = 0; w < 16; ++w) {
      float4 p = part[w * 64 + tid];
      L += p.x; A0 += p.y; A1 += p.z; A2 += p.w;
    }
    const float inv = 1.f / L;
    zbuf[tid] = make_float4(A0 * inv, A1 * inv, A2 * inv, 0.f);
  }
  __syncthreads();

  // epilogue: wave w writes queries [w*4, w*4+4)
  #pragma unroll
  for (int qi = 0; qi < 4; ++qi) {
    const int qloc = wave * 4 + qi;
    const float4 z = zbuf[qloc];
    __hip_bfloat16* outr = z2b + (size_t)(base + qc * 64 + qloc) * TCH;
    #pragma unroll
    for (int it = 0; it < 8; ++it) {
      const int c = it * 64 + lane;
      const float4 we = woL[c];
      outr[c] = __float2bfloat16(z.x*we.x + z.y*we.y + z.z*we.z + we.w);
    }
  }
}

// ---------------- fused GEMM (C = A @ W^T + bias) + residual + LayerNorm ----
// 512 blocks x 512 threads: 32 rows x full 512 cols per block; wave w owns
// cols [w*64, w*64+64). 2 blocks/CU. Register double-buffer prefetch.
template<typename LN_T, typename RES_T, bool WRITE_R>
__global__ __launch_bounds__(512, 4) void gemm_ln_kernel(
    const __hip_bfloat16* __restrict__ A,   // [16384, 512] bf16
    const __hip_bfloat16* __restrict__ W,   // [512, 512]   bf16, row = out dim
    const float* __restrict__ bias,         // [512]
    const RES_T* __restrict__ res,          // [16384, 512] residual
    __hip_bfloat16* __restrict__ Rout,      // r = res + C (if WRITE_R), bf16
    LN_T* __restrict__ LNout,               // LayerNorm(r)
    const float* __restrict__ gamma, const float* __restrict__ beta)
{
  const int row0 = blockIdx.x * 32;
  const int wave = threadIdx.x >> 6;
  const int lane = threadIdx.x & 63;
  const int l16  = lane & 15;
  const int quad = lane >> 4;
  const int n0   = wave * 64;

  f32x4 acc[2][4] = {};

  const __hip_bfloat16* Abase = A + (size_t)(row0 + l16) * TCH + quad * 8;
  const __hip_bfloat16* Wbase = W + (size_t)(n0   + l16) * TCH + quad * 8;

  bf16x8 afc[2], bfc[4], afn[2], bfn[4];
  #pragma unroll
  for (int t = 0; t < 2; ++t)
    afc[t] = *reinterpret_cast<const bf16x8*>(Abase + (size_t)t * 16 * TCH);
  #pragma unroll
  for (int t = 0; t < 4; ++t)
    bfc[t] = *reinterpret_cast<const bf16x8*>(Wbase + (size_t)t * 16 * TCH);

  for (int k0 = 0; k0 < TCH; k0 += 32) {
    if (k0 + 32 < TCH) {
      #pragma unroll
      for (int t = 0; t < 2; ++t)
        afn[t] = *reinterpret_cast<const bf16x8*>(Abase + (size_t)t * 16 * TCH + k0 + 32);
      #pragma unroll
      for (int t = 0; t < 4; ++t)
        bfn[t] = *reinterpret_cast<const bf16x8*>(Wbase + (size_t)t * 16 * TCH + k0 + 32);
    }
    #pragma unroll
    for (int mt = 0; mt < 2; ++mt)
      #pragma unroll
      for (int nt = 0; nt < 4; ++nt)
        acc[mt][nt] = __builtin_amdgcn_mfma_f32_16x16x32_bf16(afc[mt], bfc[nt], acc[mt][nt], 0, 0, 0);
    #pragma unroll
    for (int t = 0; t < 2; ++t) afc[t] = afn[t];
    #pragma unroll
    for (int t = 0; t < 4; ++t) bfc[t] = bfn[t];
  }

  __shared__ float redS[8][32];
  __shared__ float redQ[8][32];

  #pragma unroll
  for (int mt = 0; mt < 2; ++mt) {
    #pragma unroll
    for (int r = 0; r < 4; ++r) {
      const int lrow = mt*16 + quad*4 + r;
      const int grow = row0 + lrow;
      float s = 0.f, sq = 0.f;
      #pragma unroll
      for (int nt = 0; nt < 4; ++nt) {
        const int col = n0 + nt*16 + l16;
        float v = acc[mt][nt][r] + bias[col] + ld_res(&res[(size_t)grow * TCH + col]);
        acc[mt][nt][r] = v;
        if constexpr (WRITE_R) Rout[(size_t)grow * TCH + col] = __float2bfloat16(v);
        s += v; sq += v * v;
      }
      #pragma unroll
      for (int off = 1; off < 16; off <<= 1) {
        s  += __shfl_xor(s,  off, 64);
        sq += __shfl_xor(sq, off, 64);
      }
      if (l16 == 0) { redS[wave][lrow] = s; redQ[wave][lrow] = sq; }
    }
  }
  __syncthreads();

  #pragma unroll
  for (int mt = 0; mt < 2; ++mt) {
    #pragma unroll
    for (int r = 0; r < 4; ++r) {
      const int lrow = mt*16 + quad*4 + r;
      const int grow = row0 + lrow;
      float S = 0.f, Q = 0.f;
      #pragma unroll
      for (int w = 0; w < 8; ++w) { S += redS[w][lrow]; Q += redQ[w][lrow]; }
      const float mu  = S * (1.f / TCH);
      const float var = Q * (1.f / TCH) - mu * mu;
      const float rs  = rsqrtf(var + LN_EPS);
      #pragma unroll
      for (int nt = 0; nt < 4; ++nt) {
        const int col = n0 + nt*16 + l16;
        float v = (acc[mt][nt][r] - mu) * rs * gamma[col] + beta[col];
        st_ln(&LNout[(size_t)grow * TCH + col], v);
      }
    }
  }
}

// ---------------- host ------------------------------------------------------
extern "C" void kernel_launch(void* const* d_in, const int* in_sizes, int n_in,
                              void* d_out, int out_size, void* d_ws, size_t ws_size,
                              hipStream_t stream) {
  (void)in_sizes; (void)n_in; (void)out_size; (void)ws_size;
  const float* x     = (const float*)d_in[0];
  const float* wq    = (const float*)d_in[1];
  const float* bq    = (const float*)d_in[2];
  const float* wk    = (const float*)d_in[3];
  const float* bk    = (const float*)d_in[4];
  const float* wv    = (const float*)d_in[5];
  const float* bv    = (const float*)d_in[6];
  const float* wo    = (const float*)d_in[7];
  const float* bo    = (const float*)d_in[8];
  const float* w1    = (const float*)d_in[9];
  const float* b1    = (const float*)d_in[10];
  const float* w2    = (const float*)d_in[11];
  const float* b2    = (const float*)d_in[12];
  const float* gamma = (const float*)d_in[13];
  const float* beta  = (const float*)d_in[14];
  float* out = (float*)d_out;

  char* ws = (char*)d_ws;
  size_t off = 0;
  float4* q4      = (float4*)(ws + off); off += (size_t)MTOT * 16;        // 256 KB
  uint4*  kvp     = (uint4*)(ws + off);  off += (size_t)MTOT * 16;        // 256 KB
  float4* wo_eff4 = (float4*)(ws + off); off += (size_t)TCH * 16;         // 8 KB
  __hip_bfloat16* w1b = (__hip_bfloat16*)(ws + off); off += (size_t)TCH * TCH * 2;   // 512 KB
  __hip_bfloat16* w2b = (__hip_bfloat16*)(ws + off); off += (size_t)TCH * TCH * 2;   // 512 KB
  __hip_bfloat16* z2b = (__hip_bfloat16*)(ws + off); off += (size_t)MTOT * TCH * 2;  // 16 MB
  __hip_bfloat16* r1b = (__hip_bfloat16*)(ws + off); off += (size_t)MTOT * TCH * 2;  // 16 MB
  __hip_bfloat16* r0b = (__hip_bfloat16*)(ws + off); off += (size_t)MTOT * TCH * 2;  // 16 MB

  prep_kernel<<<(TCH*TCH)/256, 256, 0, stream>>>(w1, w2, wo, bo, w1b, w2b, wo_eff4);
  qkv_kernel<<<MTOT/4, 256, 0, stream>>>(x, wq, bq, wk, bk, wv, bv, q4, kvp);
  attn_kernel<<<MTOT/64, 1024, 0, stream>>>(q4, kvp, wo_eff4, z2b);
  gemm_ln_kernel<__hip_bfloat16, float, true><<<MTOT/32, 512, 0, stream>>>(
      z2b, w1b, b1, x, r0b, r1b, gamma, beta);
  gemm_ln_kernel<float, __hip_bfloat16, false><<<MTOT/32, 512, 0, stream>>>(
      r1b, w2b, b2, r0b, nullptr, out, gamma, beta);
}

// Round 4
// 236.463 us; speedup vs baseline: 1.1211x; 1.0496x over previous
//
#include <hip/hip_runtime.h>
#include <hip/hip_bf16.h>

#define TCH 512
#define MTOT 16384
#define SEQ 2048
#define LN_EPS 1e-5f

typedef __attribute__((ext_vector_type(8))) __bf16 bf16x8;
typedef __attribute__((ext_vector_type(4))) float f32x4;

__device__ __forceinline__ void st_ln(float* p, float v) { *p = v; }
__device__ __forceinline__ void st_ln(__hip_bfloat16* p, float v) { *p = __float2bfloat16(v); }
__device__ __forceinline__ float ld_res(const float* p) { return *p; }
__device__ __forceinline__ float ld_res(const __hip_bfloat16* p) { return __bfloat162float(*p); }

__device__ __forceinline__ unsigned pkbf(float a, float b) {
  union { __hip_bfloat16 h; unsigned short u; } ca, cb;
  ca.h = __float2bfloat16(a); cb.h = __float2bfloat16(b);
  return (unsigned)ca.u | ((unsigned)cb.u << 16);
}
__device__ __forceinline__ float bf_lo(unsigned u) { return __uint_as_float(u << 16); }
__device__ __forceinline__ float bf_hi(unsigned u) { return __uint_as_float(u & 0xffff0000u); }

__device__ __forceinline__ bf16x8 cvt8(float4 a, float4 b) {
  union { __hip_bfloat16 h; __bf16 v; } u;
  bf16x8 r;
  u.h = __float2bfloat16(a.x); r[0] = u.v;
  u.h = __float2bfloat16(a.y); r[1] = u.v;
  u.h = __float2bfloat16(a.z); r[2] = u.v;
  u.h = __float2bfloat16(a.w); r[3] = u.v;
  u.h = __float2bfloat16(b.x); r[4] = u.v;
  u.h = __float2bfloat16(b.y); r[5] = u.v;
  u.h = __float2bfloat16(b.z); r[6] = u.v;
  u.h = __float2bfloat16(b.w); r[7] = u.v;
  return r;
}

// log2(e)/sqrt(3): folded into wq/bq so attention uses exp2 directly
#define QSCALE 0.8329517853860118f

// ---------------- prep ------------------------------------------------------
// w1,w2 -> bf16; wo -> wo_eff (+bo in .w); wq/wk/wv -> packed bf16 [16][512]
// (rows 0-2 = wq*QSCALE, 3-5 = wk, 6-8 = wv, 9-15 = 0); qkvbias[16].
__global__ __launch_bounds__(256) void prep_kernel(
    const float* __restrict__ w1, const float* __restrict__ w2,
    const float* __restrict__ wo, const float* __restrict__ bo,
    const float* __restrict__ wq, const float* __restrict__ bq,
    const float* __restrict__ wk, const float* __restrict__ bk,
    const float* __restrict__ wv, const float* __restrict__ bv,
    __hip_bfloat16* __restrict__ w1b, __hip_bfloat16* __restrict__ w2b,
    float4* __restrict__ wo_eff4,
    __hip_bfloat16* __restrict__ wqkvb, float* __restrict__ qkvbias)
{
  int i = blockIdx.x * 256 + threadIdx.x;   // grid covers 512*512 exactly
  w1b[i] = __float2bfloat16(w1[i]);
  w2b[i] = __float2bfloat16(w2[i]);
  if (i < TCH) {
    float s0 = 0.f, s1 = 0.f, s2 = 0.f;
    #pragma unroll
    for (int h = 0; h < 6; ++h) {
      s0 += wo[i*18 + h*3 + 0];
      s1 += wo[i*18 + h*3 + 1];
      s2 += wo[i*18 + h*3 + 2];
    }
    wo_eff4[i] = make_float4(s0, s1, s2, bo[i]);
  }
  if (i < 16 * TCH) {
    int row = i >> 9, k = i & 511;
    float v;
    if      (row < 3) v = wq[row * TCH + k] * QSCALE;
    else if (row < 6) v = wk[(row - 3) * TCH + k];
    else if (row < 9) v = wv[(row - 6) * TCH + k];
    else              v = 0.f;
    wqkvb[i] = __float2bfloat16(v);
  }
  if (i < 16) {
    float v;
    if      (i < 3) v = bq[i] * QSCALE;
    else if (i < 6) v = bk[i - 3];
    else if (i < 9) v = bv[i - 6];
    else            v = 0.f;
    qkvbias[i] = v;
  }
}

// ---------------- qkv via MFMA: [16384,512] x [512,16] ----------------------
// 256 blocks x 256 thr (4 waves); wave handles 16 rows, full K. B-frags
// (wqkvb) preloaded into 64 VGPRs; x streamed fp32 with depth-2 prefetch.
__global__ __launch_bounds__(256) void qkv_kernel(
    const float* __restrict__ x,
    const __hip_bfloat16* __restrict__ wqkvb, const float* __restrict__ qkvbias,
    float4* __restrict__ q4, uint4* __restrict__ kvp)
{
  const int t = threadIdx.x, wv = t >> 6, ln = t & 63;
  const int l16 = ln & 15, quad = ln >> 4;
  const int row0 = blockIdx.x * 64 + wv * 16;

  bf16x8 bfr[16];
  #pragma unroll
  for (int ks = 0; ks < 16; ++ks)
    bfr[ks] = *reinterpret_cast<const bf16x8*>(wqkvb + l16 * TCH + ks * 32 + quad * 8);

  const float* xp = x + (size_t)(row0 + l16) * TCH + quad * 8;
  float4 xa = *(const float4*)xp, xb = *(const float4*)(xp + 4);
  f32x4 acc = {};
  #pragma unroll
  for (int ks = 0; ks < 16; ++ks) {
    float4 xa2 = {}, xb2 = {};
    if (ks < 15) {
      xa2 = *(const float4*)(xp + (ks + 1) * 32);
      xb2 = *(const float4*)(xp + (ks + 1) * 32 + 4);
    }
    bf16x8 af = cvt8(xa, xb);
    acc = __builtin_amdgcn_mfma_f32_16x16x32_bf16(af, bfr[ks], acc, 0, 0, 0);
    xa = xa2; xb = xb2;
  }

  __shared__ float tr[4][16][17];
  #pragma unroll
  for (int r = 0; r < 4; ++r) tr[wv][quad * 4 + r][l16] = acc[r];
  __syncthreads();

  if (ln < 32) {
    const int row  = ln & 15;
    const int grow = row0 + row;
    float c[9];
    #pragma unroll
    for (int j = 0; j < 9; ++j) c[j] = tr[wv][row][j] + qkvbias[j];
    if (ln < 16) {
      q4[grow] = make_float4(c[0], c[1], c[2], 0.f);   // pre-scaled
    } else {
      kvp[grow] = make_uint4(pkbf(c[3], c[4]), pkbf(c[5], c[6]), pkbf(c[7], c[8]), 0u);
    }
  }
}

// ---------------- attention + z@wo_eff epilogue (v4) ------------------------
// 256 blocks x 1024 thr. One query per lane (64/block); 16 waves split the
// 2048 keys (128 each, wave-private) -> read via wave-uniform pointer
// (scalar-load path, no LDS KV). No max-subtraction (scores O(1)).
__global__ __launch_bounds__(1024) void attn_kernel(
    const float4* __restrict__ q4, const uint4* __restrict__ kvp,
    const float4* __restrict__ wo_eff4,
    __hip_bfloat16* __restrict__ z2b)
{
  __shared__ float4 part[16 * 64];  // 16 KB
  __shared__ float4 zbuf[64];       // 1 KB
  __shared__ float4 woL[TCH];       // 8 KB  (wo_eff + bo in .w)

  const int b    = blockIdx.x >> 5;
  const int qc   = blockIdx.x & 31;
  const int base = b * SEQ;
  const int tid  = threadIdx.x;
  for (int i = tid; i < TCH; i += 1024) woL[i] = wo_eff4[i];

  const int wave = tid >> 6;
  const int lane = tid & 63;
  const float4 q = q4[base + qc * 64 + lane];   // pre-scaled by log2e/sqrt(3)

  const int wu = __builtin_amdgcn_readfirstlane(wave);
  const uint4* kvw = kvp + base + wu * 128;     // wave-uniform -> s_load

  float l = 0.f, a0 = 0.f, a1 = 0.f, a2 = 0.f;
  #pragma unroll 8
  for (int i = 0; i < 128; ++i) {
    uint4 rec = kvw[i];
    float s = bf_lo(rec.x) * q.x + bf_hi(rec.x) * q.y + bf_lo(rec.y) * q.z;
    float p = __builtin_amdgcn_exp2f(s);
    l  += p;
    a0 += p * bf_hi(rec.y);
    a1 += p * bf_lo(rec.z);
    a2 += p * bf_hi(rec.z);
  }
  part[wave * 64 + lane] = make_float4(l, a0, a1, a2);
  __syncthreads();

  if (tid < 64) {
    float L = 0.f, A0 = 0.f, A1 = 0.f, A2 = 0.f;
    #pragma unroll
    for (int w = 0; w < 16; ++w) {
      float4 p = part[w * 64 + tid];
      L += p.x; A0 += p.y; A1 += p.z; A2 += p.w;
    }
    const float inv = 1.f / L;
    zbuf[tid] = make_float4(A0 * inv, A1 * inv, A2 * inv, 0.f);
  }
  __syncthreads();

  // epilogue: wave w writes queries [w*4, w*4+4); packed 2xbf16 dword stores
  #pragma unroll
  for (int qi = 0; qi < 4; ++qi) {
    const int qloc = wave * 4 + qi;
    const float4 z = zbuf[qloc];
    unsigned* outr = (unsigned*)(z2b + (size_t)(base + qc * 64 + qloc) * TCH);
    #pragma unroll
    for (int it = 0; it < 4; ++it) {
      const int c = it * 128 + lane * 2;
      const float4 w0 = woL[c], w1 = woL[c + 1];
      outr[c >> 1] = pkbf(z.x*w0.x + z.y*w0.y + z.z*w0.z + w0.w,
                          z.x*w1.x + z.y*w1.y + z.z*w1.z + w1.w);
    }
  }
}

// ---------------- fused GEMM + residual + LayerNorm (v3: async LDS) ---------
// 256 blocks x 512 thr: 64 rows x full 512 cols. Double-buffered
// global_load_lds staging (W-tile 32 KB + A-tile 4 KB per k-step), one
// barrier per k-step. Quad-major LDS layout: wave-contiguous for the async
// load AND 2-way-only bank aliasing for ds_read_b128.
template<typename LN_T, typename RES_T, bool WRITE_R>
__global__ __launch_bounds__(512, 2) void gemm_ln_kernel(
    const __hip_bfloat16* __restrict__ A,   // [16384, 512] bf16
    const __hip_bfloat16* __restrict__ W,   // [512, 512]   bf16, row = out dim
    const float* __restrict__ bias,
    const RES_T* __restrict__ res,          // [16384, 512] residual
    __hip_bfloat16* __restrict__ Rout,      // r = res + C (if WRITE_R), bf16
    LN_T* __restrict__ LNout,               // LayerNorm(r)
    const float* __restrict__ gamma, const float* __restrict__ beta)
{
  __shared__ __align__(16) __hip_bfloat16 wt[2][4][512][8];  // 64 KB
  __shared__ __align__(16) __hip_bfloat16 at[2][4][64][8];   // 8 KB
  __shared__ float redS[8][64];
  __shared__ float redQ[8][64];

  const int t    = threadIdx.x;
  const int wv   = t >> 6, ln = t & 63;
  const int l16  = ln & 15, quad = ln >> 4;
  const int row0 = blockIdx.x * 64;
  const int n0   = wv * 64;

  auto stage = [&](int ks, int b) {
    const __hip_bfloat16* wg = W + (size_t)(n0 + ln) * TCH + ks * 32;
    #pragma unroll
    for (int j = 0; j < 4; ++j)
      __builtin_amdgcn_global_load_lds(
          (const __attribute__((address_space(1))) void*)(wg + j * 8),
          (__attribute__((address_space(3))) void*)&wt[b][j][n0 + ln][0], 16, 0, 0);
    if (wv >= 4) {               // wave-uniform branch
      const int q = wv - 4;
      __builtin_amdgcn_global_load_lds(
          (const __attribute__((address_space(1))) void*)(A + (size_t)(row0 + ln) * TCH + ks * 32 + q * 8),
          (__attribute__((address_space(3))) void*)&at[b][q][ln][0], 16, 0, 0);
    }
  };

  f32x4 acc[4][4] = {};
  stage(0, 0);
  for (int ks = 0; ks < 16; ++ks) {
    const int cur = ks & 1;
    __syncthreads();                         // drains vmcnt -> tile[cur] ready
    if (ks < 15) stage(ks + 1, cur ^ 1);     // async loads fly over compute
    bf16x8 af[4], bf[4];
    #pragma unroll
    for (int mt = 0; mt < 4; ++mt)
      af[mt] = *reinterpret_cast<const bf16x8*>(&at[cur][quad][mt * 16 + l16][0]);
    #pragma unroll
    for (int nt = 0; nt < 4; ++nt)
      bf[nt] = *reinterpret_cast<const bf16x8*>(&wt[cur][quad][n0 + nt * 16 + l16][0]);
    #pragma unroll
    for (int mt = 0; mt < 4; ++mt)
      #pragma unroll
      for (int nt = 0; nt < 4; ++nt)
        acc[mt][nt] = __builtin_amdgcn_mfma_f32_16x16x32_bf16(af[mt], bf[nt], acc[mt][nt], 0, 0, 0);
  }

  #pragma unroll
  for (int mt = 0; mt < 4; ++mt) {
    #pragma unroll
    for (int r = 0; r < 4; ++r) {
      const int lrow = mt * 16 + quad * 4 + r;
      const int grow = row0 + lrow;
      float s = 0.f, sq = 0.f;
      #pragma unroll
      for (int nt = 0; nt < 4; ++nt) {
        const int col = n0 + nt * 16 + l16;
        float v = acc[mt][nt][r] + bias[col] + ld_res(&res[(size_t)grow * TCH + col]);
        acc[mt][nt][r] = v;
        if constexpr (WRITE_R) Rout[(size_t)grow * TCH + col] = __float2bfloat16(v);
        s += v; sq += v * v;
      }
      #pragma unroll
      for (int off = 1; off < 16; off <<= 1) {
        s  += __shfl_xor(s,  off, 64);
        sq += __shfl_xor(sq, off, 64);
      }
      if (l16 == 0) { redS[wv][lrow] = s; redQ[wv][lrow] = sq; }
    }
  }
  __syncthreads();

  #pragma unroll
  for (int mt = 0; mt < 4; ++mt) {
    #pragma unroll
    for (int r = 0; r < 4; ++r) {
      const int lrow = mt * 16 + quad * 4 + r;
      const int grow = row0 + lrow;
      float S = 0.f, Q = 0.f;
      #pragma unroll
      for (int w = 0; w < 8; ++w) { S += redS[w][lrow]; Q += redQ[w][lrow]; }
      const float mu  = S * (1.f / TCH);
      const float var = Q * (1.f / TCH) - mu * mu;
      const float rs  = rsqrtf(var + LN_EPS);
      #pragma unroll
      for (int nt = 0; nt < 4; ++nt) {
        const int col = n0 + nt * 16 + l16;
        float v = (acc[mt][nt][r] - mu) * rs * gamma[col] + beta[col];
        st_ln(&LNout[(size_t)grow * TCH + col], v);
      }
    }
  }
}

// ---------------- host ------------------------------------------------------
extern "C" void kernel_launch(void* const* d_in, const int* in_sizes, int n_in,
                              void* d_out, int out_size, void* d_ws, size_t ws_size,
                              hipStream_t stream) {
  (void)in_sizes; (void)n_in; (void)out_size; (void)ws_size;
  const float* x     = (const float*)d_in[0];
  const float* wq    = (const float*)d_in[1];
  const float* bq    = (const float*)d_in[2];
  const float* wk    = (const float*)d_in[3];
  const float* bk    = (const float*)d_in[4];
  const float* wv    = (const float*)d_in[5];
  const float* bv    = (const float*)d_in[6];
  const float* wo    = (const float*)d_in[7];
  const float* bo    = (const float*)d_in[8];
  const float* w1    = (const float*)d_in[9];
  const float* b1    = (const float*)d_in[10];
  const float* w2    = (const float*)d_in[11];
  const float* b2    = (const float*)d_in[12];
  const float* gamma = (const float*)d_in[13];
  const float* beta  = (const float*)d_in[14];
  float* out = (float*)d_out;

  char* ws = (char*)d_ws;
  size_t off = 0;
  float4* q4      = (float4*)(ws + off); off += (size_t)MTOT * 16;        // 256 KB
  uint4*  kvp     = (uint4*)(ws + off);  off += (size_t)MTOT * 16;        // 256 KB
  float4* wo_eff4 = (float4*)(ws + off); off += (size_t)TCH * 16;         // 8 KB
  __hip_bfloat16* w1b   = (__hip_bfloat16*)(ws + off); off += (size_t)TCH * TCH * 2; // 512 KB
  __hip_bfloat16* w2b   = (__hip_bfloat16*)(ws + off); off += (size_t)TCH * TCH * 2; // 512 KB
  __hip_bfloat16* wqkvb = (__hip_bfloat16*)(ws + off); off += (size_t)16 * TCH * 2;  // 16 KB
  float*          qkvbias = (float*)(ws + off);        off += 64;
  __hip_bfloat16* z2b = (__hip_bfloat16*)(ws + off); off += (size_t)MTOT * TCH * 2;  // 16 MB
  __hip_bfloat16* r1b = (__hip_bfloat16*)(ws + off); off += (size_t)MTOT * TCH * 2;  // 16 MB
  __hip_bfloat16* r0b = (__hip_bfloat16*)(ws + off); off += (size_t)MTOT * TCH * 2;  // 16 MB

  prep_kernel<<<(TCH*TCH)/256, 256, 0, stream>>>(
      w1, w2, wo, bo, wq, bq, wk, bk, wv, bv, w1b, w2b, wo_eff4, wqkvb, qkvbias);
  qkv_kernel<<<MTOT/64, 256, 0, stream>>>(x, wqkvb, qkvbias, q4, kvp);
  attn_kernel<<<MTOT/64, 1024, 0, stream>>>(q4, kvp, wo_eff4, z2b);
  gemm_ln_kernel<__hip_bfloat16, float, true><<<MTOT/64, 512, 0, stream>>>(
      z2b, w1b, b1, x, r0b, r1b, gamma, beta);
  gemm_ln_kernel<float, __hip_bfloat16, false><<<MTOT/64, 512, 0, stream>>>(
      r1b, w2b, b2, r0b, nullptr, out, gamma, beta);
}

// Round 5
// 220.819 us; speedup vs baseline: 1.2005x; 1.0708x over previous
//
#include <hip/hip_runtime.h>
#include <hip/hip_bf16.h>

#define TCH 512
#define MTOT 16384
#define SEQ 2048
#define LN_EPS 1e-5f

typedef __attribute__((ext_vector_type(8))) __bf16 bf16x8;
typedef __attribute__((ext_vector_type(4))) float f32x4;

__device__ __forceinline__ unsigned pkbf(float a, float b) {
  union { __hip_bfloat16 h; unsigned short u; } ca, cb;
  ca.h = __float2bfloat16(a); cb.h = __float2bfloat16(b);
  return (unsigned)ca.u | ((unsigned)cb.u << 16);
}
__device__ __forceinline__ float bf_lo(unsigned u) { return __uint_as_float(u << 16); }
__device__ __forceinline__ float bf_hi(unsigned u) { return __uint_as_float(u & 0xffff0000u); }

__device__ __forceinline__ bf16x8 cvt8(float4 a, float4 b) {
  union { __hip_bfloat16 h; __bf16 v; } u;
  bf16x8 r;
  u.h = __float2bfloat16(a.x); r[0] = u.v;
  u.h = __float2bfloat16(a.y); r[1] = u.v;
  u.h = __float2bfloat16(a.z); r[2] = u.v;
  u.h = __float2bfloat16(a.w); r[3] = u.v;
  u.h = __float2bfloat16(b.x); r[4] = u.v;
  u.h = __float2bfloat16(b.y); r[5] = u.v;
  u.h = __float2bfloat16(b.z); r[6] = u.v;
  u.h = __float2bfloat16(b.w); r[7] = u.v;
  return r;
}

// log2(e)/sqrt(3): folded into wq/bq so attention uses exp2 directly
#define QSCALE 0.8329517853860118f

// ---------------- prep ------------------------------------------------------
__global__ __launch_bounds__(256) void prep_kernel(
    const float* __restrict__ w1, const float* __restrict__ w2,
    const float* __restrict__ wo, const float* __restrict__ bo,
    const float* __restrict__ wq, const float* __restrict__ bq,
    const float* __restrict__ wk, const float* __restrict__ bk,
    const float* __restrict__ wv, const float* __restrict__ bv,
    __hip_bfloat16* __restrict__ w1b, __hip_bfloat16* __restrict__ w2b,
    float4* __restrict__ wo_eff4,
    __hip_bfloat16* __restrict__ wqkvb, float* __restrict__ qkvbias)
{
  int i = blockIdx.x * 256 + threadIdx.x;   // grid covers 512*512 exactly
  w1b[i] = __float2bfloat16(w1[i]);
  w2b[i] = __float2bfloat16(w2[i]);
  if (i < TCH) {
    float s0 = 0.f, s1 = 0.f, s2 = 0.f;
    #pragma unroll
    for (int h = 0; h < 6; ++h) {
      s0 += wo[i*18 + h*3 + 0];
      s1 += wo[i*18 + h*3 + 1];
      s2 += wo[i*18 + h*3 + 2];
    }
    wo_eff4[i] = make_float4(s0, s1, s2, bo[i]);
  }
  if (i < 16 * TCH) {
    int row = i >> 9, k = i & 511;
    float v;
    if      (row < 3) v = wq[row * TCH + k] * QSCALE;
    else if (row < 6) v = wk[(row - 3) * TCH + k];
    else if (row < 9) v = wv[(row - 6) * TCH + k];
    else              v = 0.f;
    wqkvb[i] = __float2bfloat16(v);
  }
  if (i < 16) {
    float v;
    if      (i < 3) v = bq[i] * QSCALE;
    else if (i < 6) v = bk[i - 3];
    else if (i < 9) v = bv[i - 6];
    else            v = 0.f;
    qkvbias[i] = v;
  }
}

// ---------------- qkv via MFMA + bf16 x-copy --------------------------------
// 256 blocks x 256 thr (4 waves); wave handles 16 rows, full K. Also emits
// xb = bf16(x) (free: we convert x for the MFMA anyway).
__global__ __launch_bounds__(256) void qkv_kernel(
    const float* __restrict__ x,
    const __hip_bfloat16* __restrict__ wqkvb, const float* __restrict__ qkvbias,
    float4* __restrict__ q4, uint4* __restrict__ kvp,
    __hip_bfloat16* __restrict__ xb)
{
  const int t = threadIdx.x, wv = t >> 6, ln = t & 63;
  const int l16 = ln & 15, quad = ln >> 4;
  const int row0 = blockIdx.x * 64 + wv * 16;

  bf16x8 bfr[16];
  #pragma unroll
  for (int ks = 0; ks < 16; ++ks)
    bfr[ks] = *reinterpret_cast<const bf16x8*>(wqkvb + l16 * TCH + ks * 32 + quad * 8);

  const float* xp = x + (size_t)(row0 + l16) * TCH + quad * 8;
  __hip_bfloat16* xo = xb + (size_t)(row0 + l16) * TCH + quad * 8;

  float4 xa0 = *(const float4*)xp,        xb0 = *(const float4*)(xp + 4);
  float4 xa1 = *(const float4*)(xp + 32), xb1 = *(const float4*)(xp + 36);
  f32x4 acc = {};
  #pragma unroll
  for (int ks = 0; ks < 16; ++ks) {
    float4 xa2 = {}, xb2 = {};
    if (ks < 14) {
      xa2 = *(const float4*)(xp + (ks + 2) * 32);
      xb2 = *(const float4*)(xp + (ks + 2) * 32 + 4);
    }
    bf16x8 af = cvt8(xa0, xb0);
    *reinterpret_cast<bf16x8*>(xo + ks * 32) = af;
    acc = __builtin_amdgcn_mfma_f32_16x16x32_bf16(af, bfr[ks], acc, 0, 0, 0);
    xa0 = xa1; xb0 = xb1; xa1 = xa2; xb1 = xb2;
  }

  __shared__ float tr[4][16][17];
  #pragma unroll
  for (int r = 0; r < 4; ++r) tr[wv][quad * 4 + r][l16] = acc[r];
  __syncthreads();

  if (ln < 32) {
    const int row  = ln & 15;
    const int grow = row0 + row;
    float c[9];
    #pragma unroll
    for (int j = 0; j < 9; ++j) c[j] = tr[wv][row][j] + qkvbias[j];
    if (ln < 16) {
      q4[grow] = make_float4(c[0], c[1], c[2], 0.f);   // pre-scaled
    } else {
      kvp[grow] = make_uint4(pkbf(c[3], c[4]), pkbf(c[5], c[6]), pkbf(c[7], c[8]), 0u);
    }
  }
}

// ---------------- attention + z@wo_eff epilogue (v5: 4 ILP streams) ---------
__global__ __launch_bounds__(1024) void attn_kernel(
    const float4* __restrict__ q4, const uint4* __restrict__ kvp,
    const float4* __restrict__ wo_eff4,
    __hip_bfloat16* __restrict__ z2b)
{
  __shared__ float4 part[16 * 64];  // 16 KB
  __shared__ float4 zbuf[64];       // 1 KB
  __shared__ float4 woL[TCH];       // 8 KB

  const int b    = blockIdx.x >> 5;
  const int qc   = blockIdx.x & 31;
  const int base = b * SEQ;
  const int tid  = threadIdx.x;
  for (int i = tid; i < TCH; i += 1024) woL[i] = wo_eff4[i];

  const int wave = tid >> 6;
  const int lane = tid & 63;
  const float4 q = q4[base + qc * 64 + lane];   // pre-scaled by log2e/sqrt(3)

  const int wu = __builtin_amdgcn_readfirstlane(wave);
  const uint4* kvw = kvp + base + wu * 128;     // wave-uniform -> s_load

  float l[4] = {}, a0[4] = {}, a1[4] = {}, a2[4] = {};
  #pragma unroll 4
  for (int i = 0; i < 32; ++i) {
    #pragma unroll
    for (int s = 0; s < 4; ++s) {               // 4 independent chains
      uint4 rec = kvw[s * 32 + i];
      float sc = bf_lo(rec.x) * q.x + bf_hi(rec.x) * q.y + bf_lo(rec.y) * q.z;
      float p = __builtin_amdgcn_exp2f(sc);
      l[s]  += p;
      a0[s] += p * bf_hi(rec.y);
      a1[s] += p * bf_lo(rec.z);
      a2[s] += p * bf_hi(rec.z);
    }
  }
  part[wave * 64 + lane] = make_float4(l[0]+l[1]+l[2]+l[3],
                                       a0[0]+a0[1]+a0[2]+a0[3],
                                       a1[0]+a1[1]+a1[2]+a1[3],
                                       a2[0]+a2[1]+a2[2]+a2[3]);
  __syncthreads();

  if (tid < 64) {
    float L = 0.f, A0 = 0.f, A1 = 0.f, A2 = 0.f;
    #pragma unroll
    for (int w = 0; w < 16; ++w) {
      float4 p = part[w * 64 + tid];
      L += p.x; A0 += p.y; A1 += p.z; A2 += p.w;
    }
    const float inv = 1.f / L;
    zbuf[tid] = make_float4(A0 * inv, A1 * inv, A2 * inv, 0.f);
  }
  __syncthreads();

  #pragma unroll
  for (int qi = 0; qi < 4; ++qi) {
    const int qloc = wave * 4 + qi;
    const float4 z = zbuf[qloc];
    unsigned* outr = (unsigned*)(z2b + (size_t)(base + qc * 64 + qloc) * TCH);
    #pragma unroll
    for (int it = 0; it < 4; ++it) {
      const int c = it * 128 + lane * 2;
      const float4 w0 = woL[c], w1 = woL[c + 1];
      outr[c >> 1] = pkbf(z.x*w0.x + z.y*w0.y + z.z*w0.z + w0.w,
                          z.x*w1.x + z.y*w1.y + z.z*w1.z + w1.w);
    }
  }
}

// ---------------- GEMM 128x128 (m97 structure) + bias + residual ------------
// 512 blocks x 256 thr (4 waves). rb = bx&127 (rows), cb = bx>>7 (cols):
// the 4 col-blocks sharing an A-tile map to the same XCD (128 % 8 == 0).
// Double-buffered global_load_lds staging; per-block row partial sums out.
__global__ __launch_bounds__(256) void gemm_kernel(
    const __hip_bfloat16* __restrict__ A,   // [16384, 512]
    const __hip_bfloat16* __restrict__ W,   // [512, 512], row = out col
    const float* __restrict__ bias,
    const __hip_bfloat16* __restrict__ res, // [16384, 512]
    __hip_bfloat16* __restrict__ Cout,      // res + A@W^T + bias
    float2* __restrict__ partial)           // [4][16384] (sum, sumsq)
{
  __shared__ __align__(16) __hip_bfloat16 At[2][4][128][8];  // 16 KB
  __shared__ __align__(16) __hip_bfloat16 Wt[2][4][128][8];  // 16 KB
  __shared__ float redS[128][2];
  __shared__ float redQ[128][2];

  const int bx   = blockIdx.x;
  const int rb   = bx & 127, cb = bx >> 7;
  const int row0 = rb * 128, col0 = cb * 128;
  const int t    = threadIdx.x;
  const int w    = t >> 6, l = t & 63;
  const int l16  = l & 15, quad = l >> 4;
  const int wr   = w >> 1, wc = w & 1;
  const int srow = t & 127;                 // staging row
  const int sq0  = (t >> 7) << 1;           // staging quad base (wave-uniform)

  auto stage = [&](int ks, int b) {
    #pragma unroll
    for (int j = 0; j < 2; ++j) {
      const int q = sq0 | j;
      __builtin_amdgcn_global_load_lds(
          (const __attribute__((address_space(1))) void*)(A + (size_t)(row0 + srow) * TCH + ks * 32 + q * 8),
          (__attribute__((address_space(3))) void*)&At[b][q][srow][0], 16, 0, 0);
      __builtin_amdgcn_global_load_lds(
          (const __attribute__((address_space(1))) void*)(W + (size_t)(col0 + srow) * TCH + ks * 32 + q * 8),
          (__attribute__((address_space(3))) void*)&Wt[b][q][srow][0], 16, 0, 0);
    }
  };

  f32x4 acc[4][4] = {};
  stage(0, 0);
  for (int ks = 0; ks < 16; ++ks) {
    const int cur = ks & 1;
    __syncthreads();
    if (ks < 15) stage(ks + 1, cur ^ 1);
    bf16x8 af[4], bf[4];
    #pragma unroll
    for (int mt = 0; mt < 4; ++mt)
      af[mt] = *reinterpret_cast<const bf16x8*>(&At[cur][quad][wr * 64 + mt * 16 + l16][0]);
    #pragma unroll
    for (int nt = 0; nt < 4; ++nt)
      bf[nt] = *reinterpret_cast<const bf16x8*>(&Wt[cur][quad][wc * 64 + nt * 16 + l16][0]);
    #pragma unroll
    for (int mt = 0; mt < 4; ++mt)
      #pragma unroll
      for (int nt = 0; nt < 4; ++nt)
        acc[mt][nt] = __builtin_amdgcn_mfma_f32_16x16x32_bf16(af[mt], bf[nt], acc[mt][nt], 0, 0, 0);
  }

  #pragma unroll
  for (int mt = 0; mt < 4; ++mt) {
    #pragma unroll
    for (int r = 0; r < 4; ++r) {
      const int lrow = wr * 64 + mt * 16 + quad * 4 + r;
      const int grow = row0 + lrow;
      float s = 0.f, sq = 0.f;
      #pragma unroll
      for (int nt = 0; nt < 4; ++nt) {
        const int col = col0 + wc * 64 + nt * 16 + l16;
        float v = acc[mt][nt][r] + bias[col] + __bfloat162float(res[(size_t)grow * TCH + col]);
        Cout[(size_t)grow * TCH + col] = __float2bfloat16(v);
        s += v; sq += v * v;
      }
      #pragma unroll
      for (int off = 1; off < 16; off <<= 1) {
        s  += __shfl_xor(s,  off, 64);
        sq += __shfl_xor(sq, off, 64);
      }
      if (l16 == 0) { redS[lrow][wc] = s; redQ[lrow][wc] = sq; }
    }
  }
  __syncthreads();

  if (t < 128) {
    partial[(size_t)cb * MTOT + row0 + t] =
        make_float2(redS[t][0] + redS[t][1], redQ[t][0] + redQ[t][1]);
  }
}

// ---------------- LayerNorm from partials -----------------------------------
// 4096 blocks x 256 thr; one wave per row. Reads bf16 rows + per-row partials.
template<typename OUT_T>
__global__ __launch_bounds__(256) void ln_kernel(
    const __hip_bfloat16* __restrict__ Cin, const float2* __restrict__ partial,
    const float* __restrict__ gamma, const float* __restrict__ beta,
    OUT_T* __restrict__ out)
{
  const int t = threadIdx.x, wv = t >> 6, ln = t & 63;
  const int row = blockIdx.x * 4 + wv;

  float2 p0 = partial[row];
  float2 p1 = partial[MTOT + row];
  float2 p2 = partial[2 * MTOT + row];
  float2 p3 = partial[3 * MTOT + row];
  const float S = p0.x + p1.x + p2.x + p3.x;
  const float Q = p0.y + p1.y + p2.y + p3.y;
  const float mu  = S * (1.f / TCH);
  const float var = Q * (1.f / TCH) - mu * mu;
  const float rs  = rsqrtf(var + LN_EPS);

  const int c0 = ln * 8;
  bf16x8 vr = *reinterpret_cast<const bf16x8*>(Cin + (size_t)row * TCH + c0);
  float4 g0 = *(const float4*)(gamma + c0), g1 = *(const float4*)(gamma + c0 + 4);
  float4 b0 = *(const float4*)(beta  + c0), b1 = *(const float4*)(beta  + c0 + 4);

  float o[8];
  const float gg[8] = {g0.x,g0.y,g0.z,g0.w,g1.x,g1.y,g1.z,g1.w};
  const float bb[8] = {b0.x,b0.y,b0.z,b0.w,b1.x,b1.y,b1.z,b1.w};
  #pragma unroll
  for (int j = 0; j < 8; ++j) {
    union { __bf16 v; __hip_bfloat16 h; } u; u.v = vr[j];
    o[j] = (__bfloat162float(u.h) - mu) * rs * gg[j] + bb[j];
  }

  if constexpr (sizeof(OUT_T) == 2) {
    unsigned ov[4];
    #pragma unroll
    for (int j = 0; j < 4; ++j) ov[j] = pkbf(o[2*j], o[2*j+1]);
    *(uint4*)((__hip_bfloat16*)out + (size_t)row * TCH + c0) =
        make_uint4(ov[0], ov[1], ov[2], ov[3]);
  } else {
    float* op = (float*)out + (size_t)row * TCH + c0;
    *(float4*)op       = make_float4(o[0], o[1], o[2], o[3]);
    *(float4*)(op + 4) = make_float4(o[4], o[5], o[6], o[7]);
  }
}

// ---------------- host ------------------------------------------------------
extern "C" void kernel_launch(void* const* d_in, const int* in_sizes, int n_in,
                              void* d_out, int out_size, void* d_ws, size_t ws_size,
                              hipStream_t stream) {
  (void)in_sizes; (void)n_in; (void)out_size; (void)ws_size;
  const float* x     = (const float*)d_in[0];
  const float* wq    = (const float*)d_in[1];
  const float* bq    = (const float*)d_in[2];
  const float* wk    = (const float*)d_in[3];
  const float* bk    = (const float*)d_in[4];
  const float* wv    = (const float*)d_in[5];
  const float* bv    = (const float*)d_in[6];
  const float* wo    = (const float*)d_in[7];
  const float* bo    = (const float*)d_in[8];
  const float* w1    = (const float*)d_in[9];
  const float* b1    = (const float*)d_in[10];
  const float* w2    = (const float*)d_in[11];
  const float* b2    = (const float*)d_in[12];
  const float* gamma = (const float*)d_in[13];
  const float* beta  = (const float*)d_in[14];
  float* out = (float*)d_out;

  char* ws = (char*)d_ws;
  size_t off = 0;
  float4* q4      = (float4*)(ws + off); off += (size_t)MTOT * 16;
  uint4*  kvp     = (uint4*)(ws + off);  off += (size_t)MTOT * 16;
  float4* wo_eff4 = (float4*)(ws + off); off += (size_t)TCH * 16;
  __hip_bfloat16* w1b   = (__hip_bfloat16*)(ws + off); off += (size_t)TCH * TCH * 2;
  __hip_bfloat16* w2b   = (__hip_bfloat16*)(ws + off); off += (size_t)TCH * TCH * 2;
  __hip_bfloat16* wqkvb = (__hip_bfloat16*)(ws + off); off += (size_t)16 * TCH * 2;
  float*          qkvbias = (float*)(ws + off);        off += 64;
  __hip_bfloat16* xbb = (__hip_bfloat16*)(ws + off); off += (size_t)MTOT * TCH * 2;  // 16 MB
  __hip_bfloat16* z2b = (__hip_bfloat16*)(ws + off); off += (size_t)MTOT * TCH * 2;  // 16 MB
  __hip_bfloat16* r0b = (__hip_bfloat16*)(ws + off); off += (size_t)MTOT * TCH * 2;  // 16 MB
  __hip_bfloat16* r1b = (__hip_bfloat16*)(ws + off); off += (size_t)MTOT * TCH * 2;  // 16 MB
  __hip_bfloat16* rrb = (__hip_bfloat16*)(ws + off); off += (size_t)MTOT * TCH * 2;  // 16 MB
  float2* part1 = (float2*)(ws + off); off += (size_t)4 * MTOT * 8;                  // 512 KB
  float2* part2 = (float2*)(ws + off); off += (size_t)4 * MTOT * 8;                  // 512 KB

  prep_kernel<<<(TCH*TCH)/256, 256, 0, stream>>>(
      w1, w2, wo, bo, wq, bq, wk, bk, wv, bv, w1b, w2b, wo_eff4, wqkvb, qkvbias);
  qkv_kernel<<<MTOT/64, 256, 0, stream>>>(x, wqkvb, qkvbias, q4, kvp, xbb);
  attn_kernel<<<MTOT/64, 1024, 0, stream>>>(q4, kvp, wo_eff4, z2b);
  // r0 = x + z2 @ w1^T + b1
  gemm_kernel<<<512, 256, 0, stream>>>(z2b, w1b, b1, xbb, r0b, part1);
  // r1 = LN(r0)
  ln_kernel<__hip_bfloat16><<<MTOT/4, 256, 0, stream>>>(r0b, part1, gamma, beta, r1b);
  // rr = r0 + r1 @ w2^T + b2
  gemm_kernel<<<512, 256, 0, stream>>>(r1b, w2b, b2, r0b, rrb, part2);
  // out = LN(rr)
  ln_kernel<float><<<MTOT/4, 256, 0, stream>>>(rrb, part2, gamma, beta, out);
}